// Round 3
// baseline (3226.873 us; speedup 1.0000x reference)
//
#include <hip/hip_runtime.h>
#include <hip/hip_bf16.h>
#include <stdint.h>

// ---------------------------------------------------------------------------
// MolDis: 2x RelGraphConv(D=32, R=4) + ReLU, then per-32-row mean pool.
// Round 2: same design as round 1 (pull-model CSR conv, zero atomics in hot
// path); fixed the MAC16 macro parameter name colliding with float4's .w
// member under preprocessor substitution.
//   - counting-sort edges into a dst-CSR once per call (reused by both layers)
//   - conv kernel: ONE WAVE PER DST NODE, pull model. Lane (o = lane&31,
//     ihalf = lane>>5) holds W[r][i0..i0+15][o] for ALL 4 relations + W_loop
//     in VGPRs (80 regs); per edge: wave-uniform switch(r) + 16 FMAs.
//     Register accumulate, one shfl_xor(32), single coalesced 128 B store.
//     Self-loop + bias fused -> no accumulator pre-fill, no atomics at all.
// ---------------------------------------------------------------------------

__global__ __launch_bounds__(256) void zero_kernel(int4* p, int n4) {
    int i = blockIdx.x * 256 + threadIdx.x;
    const int st = gridDim.x * 256;
    for (; i < n4; i += st) p[i] = make_int4(0, 0, 0, 0);
}

__global__ __launch_bounds__(256) void hist_kernel(const int* __restrict__ dst, int E,
                                                   int* __restrict__ cnt) {
    int i = blockIdx.x * 256 + threadIdx.x;
    const int st = gridDim.x * 256;
    for (; i < E; i += st) atomicAdd(&cnt[dst[i]], 1);
}

// block b sums cnt[b*1024 .. b*1024+1023] -> partial[b]
__global__ __launch_bounds__(256) void scan_a(const int4* __restrict__ cnt4,
                                              int* __restrict__ partial) {
    __shared__ int lds[256];
    const int b = blockIdx.x, t = threadIdx.x;
    int4 c = cnt4[b * 256 + t];
    lds[t] = c.x + c.y + c.z + c.w;
    __syncthreads();
    for (int off = 128; off > 0; off >>= 1) {
        if (t < off) lds[t] += lds[t + off];
        __syncthreads();
    }
    if (t == 0) partial[b] = lds[0];
}

// single block: exclusive scan of partial[0..1023] in place
__global__ __launch_bounds__(1024) void scan_b(int* __restrict__ partial) {
    __shared__ int lds[1024];
    const int t = threadIdx.x;
    const int v = partial[t];
    lds[t] = v;
    __syncthreads();
    for (int off = 1; off < 1024; off <<= 1) {
        int add = (t >= off) ? lds[t - off] : 0;
        __syncthreads();
        lds[t] += add;
        __syncthreads();
    }
    partial[t] = lds[t] - v;   // exclusive
}

// block b: exclusive-scan its 1024 cnt entries, write row_ptr and fill
__global__ __launch_bounds__(256) void scan_c(const int4* __restrict__ cnt4,
                                              const int* __restrict__ partial,
                                              int* __restrict__ row_ptr,
                                              int* __restrict__ fill, int N, int E) {
    __shared__ int lds[256];
    const int b = blockIdx.x, t = threadIdx.x;
    int4 c = cnt4[b * 256 + t];
    const int s = c.x + c.y + c.z + c.w;
    lds[t] = s;
    __syncthreads();
    for (int off = 1; off < 256; off <<= 1) {
        int add = (t >= off) ? lds[t - off] : 0;
        __syncthreads();
        lds[t] += add;
        __syncthreads();
    }
    const int base = partial[b] + lds[t] - s;
    const int idx = b * 1024 + t * 4;
    int r0 = base, r1 = r0 + c.x, r2 = r1 + c.y, r3 = r2 + c.z;
    row_ptr[idx] = r0; row_ptr[idx + 1] = r1;
    row_ptr[idx + 2] = r2; row_ptr[idx + 3] = r3;
    fill[idx] = r0; fill[idx + 1] = r1; fill[idx + 2] = r2; fill[idx + 3] = r3;
    if (b == 0 && t == 0) row_ptr[N] = E;
}

__global__ __launch_bounds__(256) void fill_kernel(const int* __restrict__ src,
                                                   const int* __restrict__ dst,
                                                   const int* __restrict__ etype, int E,
                                                   int* __restrict__ fill,
                                                   int* __restrict__ col) {
    int i = blockIdx.x * 256 + threadIdx.x;
    const int st = gridDim.x * 256;
    for (; i < E; i += st) {
        int d = dst[i];
        int slot = atomicAdd(&fill[d], 1);
        col[slot] = ((etype[i] & 3) << 28) | src[i];
    }
}

#define RELU4(v) { v.x = fmaxf(v.x, 0.f); v.y = fmaxf(v.y, 0.f); \
                   v.z = fmaxf(v.z, 0.f); v.w = fmaxf(v.w, 0.f); }

// NOTE: parameter must NOT be named 'w' — the preprocessor would substitute
// the 'w' token inside 'v1.w' member accesses.
#define MAC16(WA) { \
    acc = fmaf(v0.x, WA[0],  acc); acc = fmaf(v0.y, WA[1],  acc); \
    acc = fmaf(v0.z, WA[2],  acc); acc = fmaf(v0.w, WA[3],  acc); \
    acc = fmaf(v1.x, WA[4],  acc); acc = fmaf(v1.y, WA[5],  acc); \
    acc = fmaf(v1.z, WA[6],  acc); acc = fmaf(v1.w, WA[7],  acc); \
    acc = fmaf(v2.x, WA[8],  acc); acc = fmaf(v2.y, WA[9],  acc); \
    acc = fmaf(v2.z, WA[10], acc); acc = fmaf(v2.w, WA[11], acc); \
    acc = fmaf(v3.x, WA[12], acc); acc = fmaf(v3.y, WA[13], acc); \
    acc = fmaf(v3.z, WA[14], acc); acc = fmaf(v3.w, WA[15], acc); }

// one wave per dst node: out[d] = bias + act(h[d])@Wl + sum_e W[et]^T act(h[src])
template<bool RELU>
__global__ __launch_bounds__(256) void conv_kernel(const float* __restrict__ h,
                                                   const float* __restrict__ W,
                                                   const float* __restrict__ Wl,
                                                   const float* __restrict__ bias,
                                                   const int* __restrict__ row_ptr,
                                                   const int* __restrict__ col,
                                                   float* __restrict__ out, int N) {
    const int lane = threadIdx.x & 63;
    const int o = lane & 31;          // output column
    const int ihalf = lane >> 5;      // which half of the input dim
    const int i0 = ihalf * 16;

    float wr0[16], wr1[16], wr2[16], wr3[16], wl[16];
#pragma unroll
    for (int ii = 0; ii < 16; ++ii) {
        wr0[ii] = W[0 * 1024 + (i0 + ii) * 32 + o];
        wr1[ii] = W[1 * 1024 + (i0 + ii) * 32 + o];
        wr2[ii] = W[2 * 1024 + (i0 + ii) * 32 + o];
        wr3[ii] = W[3 * 1024 + (i0 + ii) * 32 + o];
        wl[ii]  = Wl[(i0 + ii) * 32 + o];
    }
    const float bo = bias[o];

    const int wid = (blockIdx.x * 256 + threadIdx.x) >> 6;
    const int nw = (gridDim.x * 256) >> 6;
    const int chunk = (N + nw - 1) / nw;
    const int dbeg = wid * chunk;
    const int dend = min(N, dbeg + chunk);

    for (int d = dbeg; d < dend; ++d) {
        const int e0 = row_ptr[d], e1 = row_ptr[d + 1];
        // self-loop
        const float4* hp = (const float4*)(h + (size_t)d * 32 + i0);
        float4 v0 = hp[0], v1 = hp[1], v2 = hp[2], v3 = hp[3];
        if (RELU) { RELU4(v0); RELU4(v1); RELU4(v2); RELU4(v3); }
        float acc = bo;
        MAC16(wl);
        // edges (prefetch next col to break the col->h dependency chain)
        int c = (e0 < e1) ? col[e0] : 0;
        for (int e = e0; e < e1; ++e) {
            int cn = (e + 1 < e1) ? col[e + 1] : 0;
            const int r = c >> 28;
            const int s = c & 0x0FFFFFFF;
            const float4* sp = (const float4*)(h + (size_t)s * 32 + i0);
            v0 = sp[0]; v1 = sp[1]; v2 = sp[2]; v3 = sp[3];
            if (RELU) { RELU4(v0); RELU4(v1); RELU4(v2); RELU4(v3); }
            switch (r) {
                case 0:  MAC16(wr0); break;
                case 1:  MAC16(wr1); break;
                case 2:  MAC16(wr2); break;
                default: MAC16(wr3); break;
            }
            c = cn;
        }
        acc += __shfl_xor(acc, 32);
        if (ihalf == 0) out[(size_t)d * 32 + o] = acc;
    }
}

// out[m][o] = mean_a relu(pre2[m*32+a][o])
__global__ __launch_bounds__(256) void pool_kernel(const float* __restrict__ pre2,
                                                   float* __restrict__ out, int total) {
    int t = blockIdx.x * 256 + threadIdx.x;
    if (t >= total) return;
    const int m = t >> 5, o = t & 31;
    const float* p = pre2 + (size_t)m * 1024 + o;
    float s = 0.f;
#pragma unroll
    for (int a = 0; a < 32; ++a) s += fmaxf(p[a * 32], 0.f);
    out[t] = s * (1.0f / 32.0f);
}

extern "C" void kernel_launch(void* const* d_in, const int* in_sizes, int n_in,
                              void* d_out, int out_size, void* d_ws, size_t ws_size,
                              hipStream_t stream) {
    const float* x     = (const float*)d_in[0];
    const float* W     = (const float*)d_in[1];
    const float* Wl    = (const float*)d_in[2];
    const float* bias  = (const float*)d_in[3];
    const int*   src   = (const int*)d_in[4];
    const int*   dst   = (const int*)d_in[5];
    const int*   etype = (const int*)d_in[6];

    const int N = in_sizes[0] / 32;   // 1048576
    const int E = in_sizes[4];        // 4194304
    const int M = N / 32;             // 32768 molecules

    char* ws = (char*)d_ws;
    float* pre1    = (float*)ws;                              // 128 MB
    float* pre2    = (float*)(ws + (size_t)134217728);        // 128 MB
    int*   col     = (int*)(ws + (size_t)268435456);          // 16 MB
    int*   row_ptr = (int*)(ws + (size_t)285212672);          // 4 MB + 64
    int*   fill    = (int*)(ws + (size_t)289407040);          // 4 MB
    int*   cnt     = (int*)(ws + (size_t)293601344);          // 4 MB
    int*   partial = (int*)(ws + (size_t)297795648);          // 4 KB

    // ---- build dst-CSR (graph static across both layers) ----
    zero_kernel<<<1024, 256, 0, stream>>>((int4*)cnt, N / 4);
    hist_kernel<<<4096, 256, 0, stream>>>(dst, E, cnt);
    scan_a<<<N / 1024, 256, 0, stream>>>((const int4*)cnt, partial);
    scan_b<<<1, 1024, 0, stream>>>(partial);
    scan_c<<<N / 1024, 256, 0, stream>>>((const int4*)cnt, partial, row_ptr, fill, N, E);
    fill_kernel<<<4096, 256, 0, stream>>>(src, dst, etype, E, fill, col);

    // ---- layer 1 (input x, no input activation), layer 2 (relu on the fly) ----
    conv_kernel<false><<<4096, 256, 0, stream>>>(x,    W, Wl, bias, row_ptr, col, pre1, N);
    conv_kernel<true ><<<4096, 256, 0, stream>>>(pre1, W, Wl, bias, row_ptr, col, pre2, N);

    // ---- molecule mean pool of relu(pre2) ----
    pool_kernel<<<(M * 32 + 255) / 256, 256, 0, stream>>>(pre2, (float*)d_out, M * 32);
}

// Round 4
// 2805.971 us; speedup vs baseline: 1.1500x; 1.1500x over previous
//
#include <hip/hip_runtime.h>
#include <hip/hip_bf16.h>
#include <stdint.h>

// ---------------------------------------------------------------------------
// MolDis: 2x RelGraphConv(D=32, R=4) + ReLU, then per-32-row mean pool.
// Round 3: round-2's conv spilled its 80 weight VGPRs to scratch
// (VGPR_Count=68 < the 80 weights!) because the switch(r){MAC16(wrK)} arms
// tail-merged into a runtime-indexed array (rule #20). Fix: CSR keyed by
// dst*4+etype; conv does FOUR structurally-distinct compile-time sub-loops,
// one per relation, each naming its own weight array. No switch, no runtime
// indexing -> weights stay resident in VGPRs.
// Also: coalesced wave-per-molecule pool; preproc scratch aliased into pre2.
// ---------------------------------------------------------------------------

__global__ __launch_bounds__(256) void zero_kernel(int4* p, int n4) {
    int i = blockIdx.x * 256 + threadIdx.x;
    const int st = gridDim.x * 256;
    for (; i < n4; i += st) p[i] = make_int4(0, 0, 0, 0);
}

// cnt has 4N bins keyed by dst*4+etype
__global__ __launch_bounds__(256) void hist_kernel(const int* __restrict__ dst,
                                                   const int* __restrict__ etype, int E,
                                                   int* __restrict__ cnt) {
    int i = blockIdx.x * 256 + threadIdx.x;
    const int st = gridDim.x * 256;
    for (; i < E; i += st) atomicAdd(&cnt[dst[i] * 4 + (etype[i] & 3)], 1);
}

// block b sums cnt[b*1024 .. b*1024+1023] -> partial[b]   (4096 blocks)
__global__ __launch_bounds__(256) void scan_a(const int4* __restrict__ cnt4,
                                              int* __restrict__ partial) {
    __shared__ int lds[256];
    const int b = blockIdx.x, t = threadIdx.x;
    int4 c = cnt4[b * 256 + t];
    lds[t] = c.x + c.y + c.z + c.w;
    __syncthreads();
    for (int off = 128; off > 0; off >>= 1) {
        if (t < off) lds[t] += lds[t + off];
        __syncthreads();
    }
    if (t == 0) partial[b] = lds[0];
}

// single block: exclusive scan of partial[0..4095] in place (int4 per thread)
__global__ __launch_bounds__(1024) void scan_b(int* __restrict__ partial) {
    __shared__ int lds[1024];
    const int t = threadIdx.x;
    int4 v = ((const int4*)partial)[t];
    const int s = v.x + v.y + v.z + v.w;
    lds[t] = s;
    __syncthreads();
    for (int off = 1; off < 1024; off <<= 1) {
        int add = (t >= off) ? lds[t - off] : 0;
        __syncthreads();
        lds[t] += add;
        __syncthreads();
    }
    const int base = lds[t] - s;   // exclusive
    ((int4*)partial)[t] = make_int4(base, base + v.x, base + v.x + v.y,
                                    base + v.x + v.y + v.z);
}

// block b: exclusive-scan its 1024 cnt bins; write row_ptr; overwrite cnt
// in place with the same values to serve as the 'fill' cursor array.
__global__ __launch_bounds__(256) void scan_c(int4* __restrict__ cnt4,
                                              const int* __restrict__ partial,
                                              int* __restrict__ row_ptr,
                                              int B, int E) {
    __shared__ int lds[256];
    const int b = blockIdx.x, t = threadIdx.x;
    int4 c = cnt4[b * 256 + t];
    const int s = c.x + c.y + c.z + c.w;
    lds[t] = s;
    __syncthreads();
    for (int off = 1; off < 256; off <<= 1) {
        int add = (t >= off) ? lds[t - off] : 0;
        __syncthreads();
        lds[t] += add;
        __syncthreads();
    }
    const int base = partial[b] + lds[t] - s;
    const int r0 = base, r1 = r0 + c.x, r2 = r1 + c.y, r3 = r2 + c.z;
    ((int4*)row_ptr)[b * 256 + t] = make_int4(r0, r1, r2, r3);
    cnt4[b * 256 + t] = make_int4(r0, r1, r2, r3);   // fill cursors
    if (b == 0 && t == 0) row_ptr[B] = E;
}

__global__ __launch_bounds__(256) void fill_kernel(const int* __restrict__ src,
                                                   const int* __restrict__ dst,
                                                   const int* __restrict__ etype, int E,
                                                   int* __restrict__ fill,
                                                   int* __restrict__ col) {
    int i = blockIdx.x * 256 + threadIdx.x;
    const int st = gridDim.x * 256;
    for (; i < E; i += st) {
        int slot = atomicAdd(&fill[dst[i] * 4 + (etype[i] & 3)], 1);
        col[slot] = src[i];
    }
}

#define RELU4(v) { v.x = fmaxf(v.x, 0.f); v.y = fmaxf(v.y, 0.f); \
                   v.z = fmaxf(v.z, 0.f); v.w = fmaxf(v.w, 0.f); }

// param must not be named 'w' (would substitute into v1.w member access)
#define MAC16(WA) { \
    acc = fmaf(v0.x, WA[0],  acc); acc = fmaf(v0.y, WA[1],  acc); \
    acc = fmaf(v0.z, WA[2],  acc); acc = fmaf(v0.w, WA[3],  acc); \
    acc = fmaf(v1.x, WA[4],  acc); acc = fmaf(v1.y, WA[5],  acc); \
    acc = fmaf(v1.z, WA[6],  acc); acc = fmaf(v1.w, WA[7],  acc); \
    acc = fmaf(v2.x, WA[8],  acc); acc = fmaf(v2.y, WA[9],  acc); \
    acc = fmaf(v2.z, WA[10], acc); acc = fmaf(v2.w, WA[11], acc); \
    acc = fmaf(v3.x, WA[12], acc); acc = fmaf(v3.y, WA[13], acc); \
    acc = fmaf(v3.z, WA[14], acc); acc = fmaf(v3.w, WA[15], acc); }

#define LOADH(SRC) { \
    const float4* sp = (const float4*)(h + (size_t)(SRC) * 32 + i0); \
    v0 = sp[0]; v1 = sp[1]; v2 = sp[2]; v3 = sp[3]; \
    if (RELU) { RELU4(v0); RELU4(v1); RELU4(v2); RELU4(v3); } }

#define EDGELOOP(EA, EB, WN) \
    for (int e = (EA); e < (EB); ++e) { \
        const int s = col[e]; \
        LOADH(s); \
        MAC16(WN); \
    }

// one wave per dst node: out[d] = bias + act(h[d])@Wl + sum_r sum_e W[r]^T act(h[src])
template<bool RELU>
__global__ __launch_bounds__(256) void conv_kernel(const float* __restrict__ h,
                                                   const float* __restrict__ W,
                                                   const float* __restrict__ Wl,
                                                   const float* __restrict__ bias,
                                                   const int* __restrict__ row_ptr,
                                                   const int* __restrict__ col,
                                                   float* __restrict__ out, int N) {
    const int lane = threadIdx.x & 63;
    const int o = lane & 31;          // output column
    const int ihalf = lane >> 5;      // input-dim half
    const int i0 = ihalf * 16;

    float wr0[16], wr1[16], wr2[16], wr3[16], wl[16];
#pragma unroll
    for (int ii = 0; ii < 16; ++ii) {
        wr0[ii] = W[0 * 1024 + (i0 + ii) * 32 + o];
        wr1[ii] = W[1 * 1024 + (i0 + ii) * 32 + o];
        wr2[ii] = W[2 * 1024 + (i0 + ii) * 32 + o];
        wr3[ii] = W[3 * 1024 + (i0 + ii) * 32 + o];
        wl[ii]  = Wl[(i0 + ii) * 32 + o];
    }
    const float bo = bias[o];

    const int wid = (blockIdx.x * 256 + threadIdx.x) >> 6;
    const int nw = (gridDim.x * 256) >> 6;
    const int chunk = (N + nw - 1) / nw;
    const int dbeg = wid * chunk;
    const int dend = min(N, dbeg + chunk);

    for (int d = dbeg; d < dend; ++d) {
        const int4 rp = *(const int4*)(row_ptr + 4 * d);  // starts of r=0..3
        const int e4 = row_ptr[4 * d + 4];                // end of r=3
        float4 v0, v1, v2, v3;
        // self-loop + bias
        LOADH(d);
        float acc = bo;
        MAC16(wl);
        // four structurally-distinct relation sub-loops (keeps weights in VGPRs)
        EDGELOOP(rp.x, rp.y, wr0);
        EDGELOOP(rp.y, rp.z, wr1);
        EDGELOOP(rp.z, rp.w, wr2);
        EDGELOOP(rp.w, e4,   wr3);
        acc += __shfl_xor(acc, 32);
        if (ihalf == 0) out[(size_t)d * 32 + o] = acc;
    }
}

// one wave per molecule: out[m][o] = mean_a relu(pre2[m*32+a][o]); coalesced.
__global__ __launch_bounds__(256) void pool_kernel(const float* __restrict__ pre2,
                                                   float* __restrict__ out, int M) {
    const int wid = (blockIdx.x * 256 + threadIdx.x) >> 6;
    if (wid >= M) return;
    const int lane = threadIdx.x & 63;
    const int o = lane & 31, hh = lane >> 5;
    const float* p = pre2 + (size_t)wid * 1024 + hh * 16 * 32 + o;
    float s = 0.f;
#pragma unroll
    for (int a = 0; a < 16; ++a) s += fmaxf(p[a * 32], 0.f);
    s += __shfl_xor(s, 32);
    if (hh == 0) out[wid * 32 + o] = s * (1.0f / 32.0f);
}

extern "C" void kernel_launch(void* const* d_in, const int* in_sizes, int n_in,
                              void* d_out, int out_size, void* d_ws, size_t ws_size,
                              hipStream_t stream) {
    const float* x     = (const float*)d_in[0];
    const float* W     = (const float*)d_in[1];
    const float* Wl    = (const float*)d_in[2];
    const float* bias  = (const float*)d_in[3];
    const int*   src   = (const int*)d_in[4];
    const int*   dst   = (const int*)d_in[5];
    const int*   etype = (const int*)d_in[6];

    const int N = in_sizes[0] / 32;   // 1048576
    const int E = in_sizes[4];        // 4194304
    const int M = N / 32;             // 32768 molecules
    const int B = N * 4;              // 4194304 (dst,rel) bins

    char* ws = (char*)d_ws;
    float* pre1    = (float*)ws;                              // 128 MB
    float* pre2    = (float*)(ws + (size_t)134217728);        // 128 MB
    int*   col     = (int*)(ws + (size_t)268435456);          // 16 MB
    int*   row_ptr = (int*)(ws + (size_t)285212672);          // 16 MB + 64 B
    // preprocessing scratch aliased into pre2 (dead until conv2 writes it):
    int*   cnt     = (int*)pre2;                              // 16 MB (also fill)
    int*   partial = (int*)((char*)pre2 + 16777216);          // 16 KB

    // ---- build (dst,rel)-CSR (graph static across both layers) ----
    zero_kernel<<<1024, 256, 0, stream>>>((int4*)cnt, B / 4);
    hist_kernel<<<4096, 256, 0, stream>>>(dst, etype, E, cnt);
    scan_a<<<B / 1024, 256, 0, stream>>>((const int4*)cnt, partial);
    scan_b<<<1, 1024, 0, stream>>>(partial);
    scan_c<<<B / 1024, 256, 0, stream>>>((int4*)cnt, partial, row_ptr, B, E);
    fill_kernel<<<4096, 256, 0, stream>>>(src, dst, etype, E, cnt, col);

    // ---- layer 1 (input x), layer 2 (relu(pre1) on the fly) ----
    conv_kernel<false><<<4096, 256, 0, stream>>>(x,    W, Wl, bias, row_ptr, col, pre1, N);
    conv_kernel<true ><<<4096, 256, 0, stream>>>(pre1, W, Wl, bias, row_ptr, col, pre2, N);

    // ---- molecule mean pool of relu(pre2) ----
    pool_kernel<<<M / 4, 256, 0, stream>>>(pre2, (float*)d_out, M);
}

// Round 5
// 2799.502 us; speedup vs baseline: 1.1527x; 1.0023x over previous
//
#include <hip/hip_runtime.h>
#include <hip/hip_bf16.h>
#include <stdint.h>

// ---------------------------------------------------------------------------
// MolDis: 2x RelGraphConv(D=32, R=4) + ReLU, then per-32-row mean pool.
// Round 4: rounds 2-3 both lost the 80 weight values from VGPRs — the
// allocator sinks/remats the weight loads into the edge loop (VGPR_Count=60,
// ~20 GB/conv of L1 weight re-reads). This round pins them:
//   - __launch_bounds__(256, 4): explicit 128-VGPR budget (4 waves/SIMD)
//   - asm volatile("" : "+v"(w)) keep-alive after the weight loads: an
//     asm-defined value cannot be rematerialized -> must stay register-
//     resident (or visibly spill to scratch, which the profile would show).
// Everything else (dst*4+etype CSR, 4 distinct relation sub-loops, fused
// self-loop, wave-per-molecule pool) unchanged from round 3.
// ---------------------------------------------------------------------------

__global__ __launch_bounds__(256) void zero_kernel(int4* p, int n4) {
    int i = blockIdx.x * 256 + threadIdx.x;
    const int st = gridDim.x * 256;
    for (; i < n4; i += st) p[i] = make_int4(0, 0, 0, 0);
}

// cnt has 4N bins keyed by dst*4+etype
__global__ __launch_bounds__(256) void hist_kernel(const int* __restrict__ dst,
                                                   const int* __restrict__ etype, int E,
                                                   int* __restrict__ cnt) {
    int i = blockIdx.x * 256 + threadIdx.x;
    const int st = gridDim.x * 256;
    for (; i < E; i += st) atomicAdd(&cnt[dst[i] * 4 + (etype[i] & 3)], 1);
}

// block b sums cnt[b*1024 .. b*1024+1023] -> partial[b]   (4096 blocks)
__global__ __launch_bounds__(256) void scan_a(const int4* __restrict__ cnt4,
                                              int* __restrict__ partial) {
    __shared__ int lds[256];
    const int b = blockIdx.x, t = threadIdx.x;
    int4 c = cnt4[b * 256 + t];
    lds[t] = c.x + c.y + c.z + c.w;
    __syncthreads();
    for (int off = 128; off > 0; off >>= 1) {
        if (t < off) lds[t] += lds[t + off];
        __syncthreads();
    }
    if (t == 0) partial[b] = lds[0];
}

// single block: exclusive scan of partial[0..4095] in place (int4 per thread)
__global__ __launch_bounds__(1024) void scan_b(int* __restrict__ partial) {
    __shared__ int lds[1024];
    const int t = threadIdx.x;
    int4 v = ((const int4*)partial)[t];
    const int s = v.x + v.y + v.z + v.w;
    lds[t] = s;
    __syncthreads();
    for (int off = 1; off < 1024; off <<= 1) {
        int add = (t >= off) ? lds[t - off] : 0;
        __syncthreads();
        lds[t] += add;
        __syncthreads();
    }
    const int base = lds[t] - s;   // exclusive
    ((int4*)partial)[t] = make_int4(base, base + v.x, base + v.x + v.y,
                                    base + v.x + v.y + v.z);
}

// block b: exclusive-scan its 1024 cnt bins; write row_ptr; overwrite cnt
// in place with the same values to serve as the 'fill' cursor array.
__global__ __launch_bounds__(256) void scan_c(int4* __restrict__ cnt4,
                                              const int* __restrict__ partial,
                                              int* __restrict__ row_ptr,
                                              int B, int E) {
    __shared__ int lds[256];
    const int b = blockIdx.x, t = threadIdx.x;
    int4 c = cnt4[b * 256 + t];
    const int s = c.x + c.y + c.z + c.w;
    lds[t] = s;
    __syncthreads();
    for (int off = 1; off < 256; off <<= 1) {
        int add = (t >= off) ? lds[t - off] : 0;
        __syncthreads();
        lds[t] += add;
        __syncthreads();
    }
    const int base = partial[b] + lds[t] - s;
    const int r0 = base, r1 = r0 + c.x, r2 = r1 + c.y, r3 = r2 + c.z;
    ((int4*)row_ptr)[b * 256 + t] = make_int4(r0, r1, r2, r3);
    cnt4[b * 256 + t] = make_int4(r0, r1, r2, r3);   // fill cursors
    if (b == 0 && t == 0) row_ptr[B] = E;
}

__global__ __launch_bounds__(256) void fill_kernel(const int* __restrict__ src,
                                                   const int* __restrict__ dst,
                                                   const int* __restrict__ etype, int E,
                                                   int* __restrict__ fill,
                                                   int* __restrict__ col) {
    int i = blockIdx.x * 256 + threadIdx.x;
    const int st = gridDim.x * 256;
    for (; i < E; i += st) {
        int slot = atomicAdd(&fill[dst[i] * 4 + (etype[i] & 3)], 1);
        col[slot] = src[i];
    }
}

#define RELU4(v) { v.x = fmaxf(v.x, 0.f); v.y = fmaxf(v.y, 0.f); \
                   v.z = fmaxf(v.z, 0.f); v.w = fmaxf(v.w, 0.f); }

// param must not be named 'w' (would substitute into v1.w member access)
#define MAC16(WA) { \
    acc = fmaf(v0.x, WA[0],  acc); acc = fmaf(v0.y, WA[1],  acc); \
    acc = fmaf(v0.z, WA[2],  acc); acc = fmaf(v0.w, WA[3],  acc); \
    acc = fmaf(v1.x, WA[4],  acc); acc = fmaf(v1.y, WA[5],  acc); \
    acc = fmaf(v1.z, WA[6],  acc); acc = fmaf(v1.w, WA[7],  acc); \
    acc = fmaf(v2.x, WA[8],  acc); acc = fmaf(v2.y, WA[9],  acc); \
    acc = fmaf(v2.z, WA[10], acc); acc = fmaf(v2.w, WA[11], acc); \
    acc = fmaf(v3.x, WA[12], acc); acc = fmaf(v3.y, WA[13], acc); \
    acc = fmaf(v3.z, WA[14], acc); acc = fmaf(v3.w, WA[15], acc); }

#define LOADH(SRC) { \
    const float4* sp = (const float4*)(h + (size_t)(SRC) * 32 + i0); \
    v0 = sp[0]; v1 = sp[1]; v2 = sp[2]; v3 = sp[3]; \
    if (RELU) { RELU4(v0); RELU4(v1); RELU4(v2); RELU4(v3); } }

#define EDGELOOP(EA, EB, WN) \
    for (int e = (EA); e < (EB); ++e) { \
        const int s = col[e]; \
        LOADH(s); \
        MAC16(WN); \
    }

// one wave per dst node: out[d] = bias + act(h[d])@Wl + sum_r sum_e W[r]^T act(h[src])
template<bool RELU>
__global__ __launch_bounds__(256, 4) void conv_kernel(const float* __restrict__ h,
                                                      const float* __restrict__ W,
                                                      const float* __restrict__ Wl,
                                                      const float* __restrict__ bias,
                                                      const int* __restrict__ row_ptr,
                                                      const int* __restrict__ col,
                                                      float* __restrict__ out, int N) {
    const int lane = threadIdx.x & 63;
    const int o = lane & 31;          // output column
    const int ihalf = lane >> 5;      // input-dim half
    const int i0 = ihalf * 16;

    float wr0[16], wr1[16], wr2[16], wr3[16], wl[16];
#pragma unroll
    for (int ii = 0; ii < 16; ++ii) {
        wr0[ii] = W[0 * 1024 + (i0 + ii) * 32 + o];
        wr1[ii] = W[1 * 1024 + (i0 + ii) * 32 + o];
        wr2[ii] = W[2 * 1024 + (i0 + ii) * 32 + o];
        wr3[ii] = W[3 * 1024 + (i0 + ii) * 32 + o];
        wl[ii]  = Wl[(i0 + ii) * 32 + o];
    }
    float bo = bias[o];
    // Pin weights in VGPRs: asm-defined values cannot be rematerialized, so
    // the allocator cannot sink the W loads back into the edge loops.
#pragma unroll
    for (int ii = 0; ii < 16; ++ii) {
        asm volatile("" : "+v"(wr0[ii]), "+v"(wr1[ii]), "+v"(wr2[ii]),
                          "+v"(wr3[ii]), "+v"(wl[ii]));
    }
    asm volatile("" : "+v"(bo));

    const int wid = (blockIdx.x * 256 + threadIdx.x) >> 6;
    const int nw = (gridDim.x * 256) >> 6;
    const int chunk = (N + nw - 1) / nw;
    const int dbeg = wid * chunk;
    const int dend = min(N, dbeg + chunk);

    for (int d = dbeg; d < dend; ++d) {
        const int4 rp = *(const int4*)(row_ptr + 4 * d);  // starts of r=0..3
        const int e4 = row_ptr[4 * d + 4];                // end of r=3
        float4 v0, v1, v2, v3;
        // self-loop + bias
        LOADH(d);
        float acc = bo;
        MAC16(wl);
        // four structurally-distinct relation sub-loops (weights stay in VGPRs)
        EDGELOOP(rp.x, rp.y, wr0);
        EDGELOOP(rp.y, rp.z, wr1);
        EDGELOOP(rp.z, rp.w, wr2);
        EDGELOOP(rp.w, e4,   wr3);
        acc += __shfl_xor(acc, 32);
        if (ihalf == 0) out[(size_t)d * 32 + o] = acc;
    }
}

// one wave per molecule: out[m][o] = mean_a relu(pre2[m*32+a][o]); coalesced.
__global__ __launch_bounds__(256) void pool_kernel(const float* __restrict__ pre2,
                                                   float* __restrict__ out, int M) {
    const int wid = (blockIdx.x * 256 + threadIdx.x) >> 6;
    if (wid >= M) return;
    const int lane = threadIdx.x & 63;
    const int o = lane & 31, hh = lane >> 5;
    const float* p = pre2 + (size_t)wid * 1024 + hh * 16 * 32 + o;
    float s = 0.f;
#pragma unroll
    for (int a = 0; a < 16; ++a) s += fmaxf(p[a * 32], 0.f);
    s += __shfl_xor(s, 32);
    if (hh == 0) out[wid * 32 + o] = s * (1.0f / 32.0f);
}

extern "C" void kernel_launch(void* const* d_in, const int* in_sizes, int n_in,
                              void* d_out, int out_size, void* d_ws, size_t ws_size,
                              hipStream_t stream) {
    const float* x     = (const float*)d_in[0];
    const float* W     = (const float*)d_in[1];
    const float* Wl    = (const float*)d_in[2];
    const float* bias  = (const float*)d_in[3];
    const int*   src   = (const int*)d_in[4];
    const int*   dst   = (const int*)d_in[5];
    const int*   etype = (const int*)d_in[6];

    const int N = in_sizes[0] / 32;   // 1048576
    const int E = in_sizes[4];        // 4194304
    const int M = N / 32;             // 32768 molecules
    const int B = N * 4;              // 4194304 (dst,rel) bins

    char* ws = (char*)d_ws;
    float* pre1    = (float*)ws;                              // 128 MB
    float* pre2    = (float*)(ws + (size_t)134217728);        // 128 MB
    int*   col     = (int*)(ws + (size_t)268435456);          // 16 MB
    int*   row_ptr = (int*)(ws + (size_t)285212672);          // 16 MB + 64 B
    // preprocessing scratch aliased into pre2 (dead until conv2 writes it):
    int*   cnt     = (int*)pre2;                              // 16 MB (also fill)
    int*   partial = (int*)((char*)pre2 + 16777216);          // 16 KB

    // ---- build (dst,rel)-CSR (graph static across both layers) ----
    zero_kernel<<<1024, 256, 0, stream>>>((int4*)cnt, B / 4);
    hist_kernel<<<4096, 256, 0, stream>>>(dst, etype, E, cnt);
    scan_a<<<B / 1024, 256, 0, stream>>>((const int4*)cnt, partial);
    scan_b<<<1, 1024, 0, stream>>>(partial);
    scan_c<<<B / 1024, 256, 0, stream>>>((int4*)cnt, partial, row_ptr, B, E);
    fill_kernel<<<4096, 256, 0, stream>>>(src, dst, etype, E, cnt, col);

    // ---- layer 1 (input x), layer 2 (relu(pre1) on the fly) ----
    conv_kernel<false><<<4096, 256, 0, stream>>>(x,    W, Wl, bias, row_ptr, col, pre1, N);
    conv_kernel<true ><<<4096, 256, 0, stream>>>(pre1, W, Wl, bias, row_ptr, col, pre2, N);

    // ---- molecule mean pool of relu(pre2) ----
    pool_kernel<<<M / 4, 256, 0, stream>>>(pre2, (float*)d_out, M);
}